// Round 4
// baseline (178.684 us; speedup 1.0000x reference)
//
#include <hip/hip_runtime.h>
#include <hip/hip_cooperative_groups.h>

namespace cg = cooperative_groups;

// Problem constants (fixed by reference)
#define GS    256
#define PARAM 128
#define KC    32
#define I1    64
#define I2    32
#define PK    96        // PARAM - KC
#define B_    4
#define NROWS (B_ * GS) // 1024
#define EPS   1e-3f
#define KDIV_INV (1.0f / 16.0f)

// Workspace layout (float offsets) — only U and W (BN folding is inline)
constexpr int U_OFF = 0;            // NROWS*I1
constexpr int W_OFF = NROWS * I1;   // NROWS*I1

__device__ __forceinline__ float rdlane(float v, int l) {
    return __uint_as_float(__builtin_amdgcn_readlane(__float_as_uint(v), l));
}

// Fused kernel. phase==0: both phases + grid.sync (cooperative launch).
// phase==1 / phase==2: fallback split launches (no grid sync executed).
//
// CODEGEN NOTE (r1/r3 evidence): with the folded weights held in C arrays
// (m2col[64], m3a[32], m3b[32]), this fused function shipped VGPR_Count=80
// both with and without a launch-bounds cap — i.e. the arrays were demoted
// to scratch by the middle-end (failed SROA), not spilled by RA. Fix: 128
// *named scalar* registers (macro-generated) + straight-line inner loops.
// No alloca exists, so scratch demotion is impossible by construction.
// amdgpu_waves_per_eu(2) relaxes the RA occupancy target (VGPR budget 256
// >> ~190 needed) so RA has no reason to spill either.
__global__ __launch_bounds__(256) __attribute__((amdgpu_waves_per_eu(2)))
void glmlp_fused(
    const float* __restrict__ mat, const float* __restrict__ val,
    const float* __restrict__ M1, const float* __restrict__ B1,
    const float* __restrict__ M2, const float* __restrict__ B2,
    const float* __restrict__ M3, const float* __restrict__ B3,
    const float* __restrict__ g1, const float* __restrict__ b1,
    const float* __restrict__ m1, const float* __restrict__ v1,
    const float* __restrict__ g2, const float* __restrict__ b2,
    const float* __restrict__ m2, const float* __restrict__ v2,
    const float* __restrict__ g3, const float* __restrict__ b3,
    const float* __restrict__ m3, const float* __restrict__ v3,
    float* __restrict__ ws, float* __restrict__ out, int phase)
{
    __shared__ float vrow[PARAM];       // 512 B
    __shared__ float red[4][I1];        // 1 KB
    __shared__ int   acty[GS];          // 1 KB
    __shared__ float partial[4][PK];    // 1.5 KB
    __shared__ int   cnt;

    const int nb   = gridDim.x;
    const int t    = threadIdx.x;
    const int lane = t & 63;
    const int w    = t >> 6;            // wave id 0..3
    const int jj   = lane & 31;

    // ---------------- Phase 1 ----------------
    if (phase != 2) {
        for (int r = blockIdx.x; r < NROWS; r += nb) {
            if (t < PARAM) vrow[t] = val[r * PARAM + t];
            if (t < KC)    out[r * PARAM + t] = val[r * PARAM + t];
            __syncthreads();

            const int i = lane;
            const int q = w;                              // 0..3
            // q=0,1 -> T (M1 top half); q=2,3 -> W (M1 bottom half)
            const float* __restrict__ Mb = M1 + ((q >> 1) ? (PARAM * I1) : 0);
            const int p0 = (q & 1) * 64;
            float aa = 0.f, bb = 0.f;                     // dual chains
            #pragma unroll 8
            for (int p = 0; p < 64; p += 2) {
                aa = fmaf(vrow[p0 + p],     Mb[(p0 + p) * I1 + i],     aa);
                bb = fmaf(vrow[p0 + p + 1], Mb[(p0 + p + 1) * I1 + i], bb);
            }
            red[q][i] = aa + bb;
            __syncthreads();

            if (q == 0) {
                const float T  = red[0][i] + red[1][i];
                const float Wv = red[2][i] + red[3][i];
                const float s1 = g1[i] * rsqrtf(v1[i] + EPS);
                ws[U_OFF + r * I1 + i] = (T - Wv) * s1;
                ws[W_OFF + r * I1 + i] = Wv * s1;
            }
            // loop-top __syncthreads protects vrow/red reuse
        }
    }

    if (phase == 0) {
        cg::this_grid().sync();
        // Keep phase-2 weight loads BELOW the grid sync.
        asm volatile("" ::: "memory");
    }

    // ---------------- Phase 2 ----------------
    if (phase != 1) {
        // Inline BN folding into 128 NAMED per-lane registers.
        // lane (h=lane>>5, jj=lane&31):
        //   m2_S   = M2f[S][jj]      (full column, dup across halves)
        //   m3a_K  = M3f[K][lane]    (col k0 = lane)
        //   m3b_K  = M3f[K][64+jj]   (col k1 = 64+jj, dup across halves)
        const float s2  = g2[jj]      * rsqrtf(v2[jj]      + EPS);
        const float s3a = g3[lane]    * rsqrtf(v3[lane]    + EPS);
        const float s3b = g3[64 + jj] * rsqrtf(v3[64 + jj] + EPS);

#define DM2_(S)  const float m2_##S  = M2[(S) * I2 + jj] * s2;
        DM2_(0)  DM2_(1)  DM2_(2)  DM2_(3)  DM2_(4)  DM2_(5)  DM2_(6)  DM2_(7)
        DM2_(8)  DM2_(9)  DM2_(10) DM2_(11) DM2_(12) DM2_(13) DM2_(14) DM2_(15)
        DM2_(16) DM2_(17) DM2_(18) DM2_(19) DM2_(20) DM2_(21) DM2_(22) DM2_(23)
        DM2_(24) DM2_(25) DM2_(26) DM2_(27) DM2_(28) DM2_(29) DM2_(30) DM2_(31)
        DM2_(32) DM2_(33) DM2_(34) DM2_(35) DM2_(36) DM2_(37) DM2_(38) DM2_(39)
        DM2_(40) DM2_(41) DM2_(42) DM2_(43) DM2_(44) DM2_(45) DM2_(46) DM2_(47)
        DM2_(48) DM2_(49) DM2_(50) DM2_(51) DM2_(52) DM2_(53) DM2_(54) DM2_(55)
        DM2_(56) DM2_(57) DM2_(58) DM2_(59) DM2_(60) DM2_(61) DM2_(62) DM2_(63)
#undef DM2_

#define DM3_(K)  const float m3a_##K = M3[(K) * PK + lane]    * s3a; \
                 const float m3b_##K = M3[(K) * PK + 64 + jj] * s3b;
        DM3_(0)  DM3_(1)  DM3_(2)  DM3_(3)  DM3_(4)  DM3_(5)  DM3_(6)  DM3_(7)
        DM3_(8)  DM3_(9)  DM3_(10) DM3_(11) DM3_(12) DM3_(13) DM3_(14) DM3_(15)
        DM3_(16) DM3_(17) DM3_(18) DM3_(19) DM3_(20) DM3_(21) DM3_(22) DM3_(23)
        DM3_(24) DM3_(25) DM3_(26) DM3_(27) DM3_(28) DM3_(29) DM3_(30) DM3_(31)
#undef DM3_

        const float s1l = g1[lane] * rsqrtf(v1[lane] + EPS);
        const float c1l = B1[lane] * s1l + b1[lane] - m1[lane] * s1l;
        const float c2j = B2[jj]   * s2  + b2[jj]   - m2[jj]   * s2;
        const float c30 = B3[lane]    * s3a + b3[lane]    - m3[lane]    * s3a;
        const float c31 = B3[64 + jj] * s3b + b3[64 + jj] - m3[64 + jj] * s3b;

        const float* __restrict__ W = ws + W_OFF;

        for (int r = blockIdx.x; r < NROWS; r += nb) {
            const int wbase = r & ~(GS - 1);    // b * GS
            if (t == 0) cnt = 0;
            __syncthreads();                    // cnt=0 visible; guards acty reuse
            const float mv = mat[r * GS + t];
            if (mv != 0.0f) acty[atomicAdd(&cnt, 1)] = t;   // values are exactly 0/1
            const float ux = ws[U_OFF + r * I1 + lane] + c1l;
            __syncthreads();
            const int n = cnt;

            float acc0 = 0.f, acc1 = 0.f;

            int p = w;
            float wv = (p < n) ? W[(wbase + acty[p]) * I1 + lane] : 0.f;
            while (p < n) {
                const int pn = p + 4;
                const float wvn = (pn < n) ? W[(wbase + acty[pn]) * I1 + lane] : 0.f;

                // Layer 1 (register): lane holds H1[lane]
                const float h1 = fmaxf(ux + wv, 0.f);

                // Layer 2: full dot for column jj via 64 uniform readlane
                // broadcasts; 4 interleaved chains (dep 16). Straight-line.
                float a0 = 0.f, a1 = 0.f, a2 = 0.f, a3 = 0.f;
#define L2_(S0,S1,S2,S3) \
                a0 = fmaf(rdlane(h1, S0), m2_##S0, a0); \
                a1 = fmaf(rdlane(h1, S1), m2_##S1, a1); \
                a2 = fmaf(rdlane(h1, S2), m2_##S2, a2); \
                a3 = fmaf(rdlane(h1, S3), m2_##S3, a3);
                L2_(0,1,2,3)     L2_(4,5,6,7)     L2_(8,9,10,11)   L2_(12,13,14,15)
                L2_(16,17,18,19) L2_(20,21,22,23) L2_(24,25,26,27) L2_(28,29,30,31)
                L2_(32,33,34,35) L2_(36,37,38,39) L2_(40,41,42,43) L2_(44,45,46,47)
                L2_(48,49,50,51) L2_(52,53,54,55) L2_(56,57,58,59) L2_(60,61,62,63)
#undef L2_
                const float h2 = fmaxf((a0 + a1) + (a2 + a3) + c2j, 0.f);

                // Layer 3: 32 uniform broadcasts serve both output columns
                // k0 = lane, k1 = 64+jj. Dual chains each. Straight-line.
                float d0a = c30, d0b = 0.f, d1a = c31, d1b = 0.f;
#define L3_(K0,K1) { \
                const float he = rdlane(h2, K0); \
                const float ho = rdlane(h2, K1); \
                d0a = fmaf(he, m3a_##K0, d0a); \
                d0b = fmaf(ho, m3a_##K1, d0b); \
                d1a = fmaf(he, m3b_##K0, d1a); \
                d1b = fmaf(ho, m3b_##K1, d1b); }
                L3_(0,1)   L3_(2,3)   L3_(4,5)   L3_(6,7)
                L3_(8,9)   L3_(10,11) L3_(12,13) L3_(14,15)
                L3_(16,17) L3_(18,19) L3_(20,21) L3_(22,23)
                L3_(24,25) L3_(26,27) L3_(28,29) L3_(30,31)
#undef L3_
                acc0 += fmaxf(d0a + d0b, 0.f);
                acc1 += fmaxf(d1a + d1b, 0.f);

                wv = wvn;
                p = pn;
            }

            partial[w][lane] = acc0;
            if (lane < 32) partial[w][64 + lane] = acc1;  // halves hold identical acc1
            __syncthreads();

            if (t < PK) {
                float v = (partial[0][t] + partial[1][t] +
                           partial[2][t] + partial[3][t]) * KDIV_INV;
                v = fminf(fmaxf(v, -1.0f), 1.0f);
                out[r * PARAM + KC + t] = v;
            }
            __syncthreads();                    // partial reuse across rows
        }
    }
}

extern "C" void kernel_launch(void* const* d_in, const int* in_sizes, int n_in,
                              void* d_out, int out_size, void* d_ws, size_t ws_size,
                              hipStream_t stream) {
    const float* mat = (const float*)d_in[0];
    const float* val = (const float*)d_in[1];
    const float* M1  = (const float*)d_in[2];
    const float* B1  = (const float*)d_in[3];
    const float* M2  = (const float*)d_in[4];
    const float* B2  = (const float*)d_in[5];
    const float* M3  = (const float*)d_in[6];
    const float* B3  = (const float*)d_in[7];
    const float* g1  = (const float*)d_in[8];
    const float* b1  = (const float*)d_in[9];
    const float* m1  = (const float*)d_in[10];
    const float* v1  = (const float*)d_in[11];
    const float* g2  = (const float*)d_in[12];
    const float* b2  = (const float*)d_in[13];
    const float* m2  = (const float*)d_in[14];
    const float* v2  = (const float*)d_in[15];
    const float* g3  = (const float*)d_in[16];
    const float* b3  = (const float*)d_in[17];
    const float* m3  = (const float*)d_in[18];
    const float* v3  = (const float*)d_in[19];

    float* ws  = (float*)d_ws;
    float* out = (float*)d_out;

    // Cooperative path only if the device supports it AND the occupancy
    // query succeeds. Grid = CUs * min(occ, 4), clamped to NROWS — the
    // min() keeps an optimistic occupancy answer from oversubscribing
    // residency and deadlocking grid.sync().
    int coop_ok = 0;
    (void)hipDeviceGetAttribute(&coop_ok, hipDeviceAttributeCooperativeLaunch, 0);
    int occ = 0;
    hipError_t qe = hipOccupancyMaxActiveBlocksPerMultiprocessor(
        &occ, (const void*)glmlp_fused, 256, 0);
    bool try_coop = coop_ok && (qe == hipSuccess) && (occ >= 1);
    int bpc = occ < 1 ? 1 : (occ > 4 ? 4 : occ);
    int grid = 256 * bpc;
    if (grid > NROWS) grid = NROWS;

    hipError_t le = hipErrorUnknown;
    if (try_coop) {
        int phase0 = 0;
        void* args[] = {
            (void*)&mat, (void*)&val, (void*)&M1, (void*)&B1,
            (void*)&M2,  (void*)&B2,  (void*)&M3, (void*)&B3,
            (void*)&g1, (void*)&b1, (void*)&m1, (void*)&v1,
            (void*)&g2, (void*)&b2, (void*)&m2, (void*)&v2,
            (void*)&g3, (void*)&b3, (void*)&m3, (void*)&v3,
            (void*)&ws, (void*)&out, (void*)&phase0
        };
        le = hipLaunchCooperativeKernel((const void*)glmlp_fused,
                                        dim3(grid), dim3(256), args, 0, stream);
    }

    if (le != hipSuccess) {
        // Fallback: same kernel as two plain phase launches (old behavior).
        (void)hipGetLastError();
        hipLaunchKernelGGL(glmlp_fused, dim3(NROWS), dim3(256), 0, stream,
                           mat, val, M1, B1, M2, B2, M3, B3,
                           g1, b1, m1, v1, g2, b2, m2, v2, g3, b3, m3, v3,
                           ws, out, 1);
        hipLaunchKernelGGL(glmlp_fused, dim3(NROWS), dim3(256), 0, stream,
                           mat, val, M1, B1, M2, B2, M3, B3,
                           g1, b1, m1, v1, g2, b2, m2, v2, g3, b3, m3, v3,
                           ws, out, 2);
    }
}

// Round 5
// 142.161 us; speedup vs baseline: 1.2569x; 1.2569x over previous
//
#include <hip/hip_runtime.h>

// Problem constants (fixed by reference)
#define GS    256
#define PARAM 128
#define KC    32
#define I1    64
#define I2    32
#define PK    96        // PARAM - KC
#define B_    4
#define NROWS (B_ * GS) // 1024
#define EPS   1e-3f
#define KDIV_INV (1.0f / 16.0f)
#define NT    8         // pair-tile per iteration: 2 pairs per wave

__device__ __forceinline__ float rdlane(float v, int l) {
    return __uint_as_float(__builtin_amdgcn_readlane(__float_as_uint(v), l));
}

// Single self-contained kernel: one block per (b,x) row, 4 waves.
// No workspace, no second dispatch, no grid sync.
//
// Per block:
//   1. A-style quarter-dots give this row's u = (T - W_r)*s1 + c1.
//   2. Mask row compacted into acty[] (values are exactly 0.0/1.0).
//   3. BN-folded weights live in per-lane REGISTER arrays (m2col/m3a/m3b)
//      — same array + unrolled-constant-index shape as the round-0
//      standalone kernel B, which register-allocated correctly (the
//      fused/cg variants spilled to 80 VGPR three rounds running; this
//      standalone context is the proven-good one).
//   4. Tile loop over active pairs (NT=8/tile): stage the tile's val rows
//      in LDS, each wave recomputes W_y for its 2 pairs sharing ONE pass
//      over M1bot (L1-resident), then runs the register MLP per pair.
//      W-recompute redundancy is ~134M MACs grid-wide ≈ 2 µs — the price
//      of deleting kernel A, its launch, the inter-kernel drain, and all
//      workspace traffic.
__global__ __launch_bounds__(256) void glmlp_one(
    const float* __restrict__ mat, const float* __restrict__ val,
    const float* __restrict__ M1, const float* __restrict__ B1,
    const float* __restrict__ M2, const float* __restrict__ B2,
    const float* __restrict__ M3, const float* __restrict__ B3,
    const float* __restrict__ g1, const float* __restrict__ b1,
    const float* __restrict__ m1, const float* __restrict__ v1,
    const float* __restrict__ g2, const float* __restrict__ b2,
    const float* __restrict__ m2, const float* __restrict__ v2,
    const float* __restrict__ g3, const float* __restrict__ b3,
    const float* __restrict__ m3, const float* __restrict__ v3,
    float* __restrict__ out)
{
    __shared__ float vrow[PARAM];        // 512 B  : val row r
    __shared__ float red[4][I1];         // 1 KB   : quarter-dot reduction
    __shared__ int   acty[GS];           // 1 KB   : compacted active y
    __shared__ float partial[4][PK];     // 1.5 KB : cross-wave acc reduce
    __shared__ float vstage[NT][PARAM];  // 4 KB   : staged val rows (tile)
    __shared__ int   cnt;

    const int r     = blockIdx.x;
    const int t     = threadIdx.x;
    const int lane  = t & 63;
    const int w     = t >> 6;            // wave id 0..3
    const int jj    = lane & 31;
    const int wbase = r & ~(GS - 1);     // b * GS

    if (t == 0)     cnt = 0;
    if (t < PARAM)  vrow[t] = val[r * PARAM + t];
    // exact copy: con = val[:, :, :KC]
    if (t < KC)     out[r * PARAM + t] = val[r * PARAM + t];
    __syncthreads();

    // ---- 1. quarter-dots for row r: T (waves 0,1), W_r (waves 2,3) ----
    {
        const float* __restrict__ Mb = M1 + ((w >> 1) ? (PARAM * I1) : 0);
        const int p0 = (w & 1) * 64;
        float aa = 0.f, bb = 0.f;                    // dual chains
        #pragma unroll 8
        for (int p = 0; p < 64; p += 2) {
            aa = fmaf(vrow[p0 + p],     Mb[(p0 + p) * I1 + lane],     aa);
            bb = fmaf(vrow[p0 + p + 1], Mb[(p0 + p + 1) * I1 + lane], bb);
        }
        red[w][lane] = aa + bb;
    }

    // ---- 2. compact the mask row (between the same barrier pair) ----
    const float mv = mat[r * GS + t];
    if (mv != 0.0f) acty[atomicAdd(&cnt, 1)] = t;
    __syncthreads();
    const int n = cnt;

    // ---- 3. BN folding into registers (round-0-B array style) ----
    const float s1l = g1[lane] * rsqrtf(v1[lane] + EPS);
    const float c1l = B1[lane] * s1l + b1[lane] - m1[lane] * s1l;
    const float T   = red[0][lane] + red[1][lane];
    const float Wr  = red[2][lane] + red[3][lane];
    const float ux  = (T - Wr) * s1l + c1l;

    const float s2 = g2[jj] * rsqrtf(v2[jj] + EPS);
    float m2col[I1];                     // 64 VGPR
    #pragma unroll
    for (int s = 0; s < I1; ++s)
        m2col[s] = M2[s * I2 + jj] * s2;

    const float s3a = g3[lane]    * rsqrtf(v3[lane]    + EPS);
    const float s3b = g3[64 + jj] * rsqrtf(v3[64 + jj] + EPS);
    float m3a[I2], m3b[I2];              // 64 VGPR
    #pragma unroll
    for (int k = 0; k < I2; ++k) {
        m3a[k] = M3[k * PK + lane]    * s3a;
        m3b[k] = M3[k * PK + 64 + jj] * s3b;
    }

    const float c2j = B2[jj]      * s2  + b2[jj]      - m2[jj]      * s2;
    const float c30 = B3[lane]    * s3a + b3[lane]    - m3[lane]    * s3a;
    const float c31 = B3[64 + jj] * s3b + b3[64 + jj] - m3[64 + jj] * s3b;

    const float* __restrict__ Mlo = M1 + PARAM * I1;   // M1 bottom [128][64]

    float acc0 = 0.f, acc1 = 0.f;

// register MLP for one pair; consumes WV (pre-scale by s1l applied here)
#define MLP_BODY(WV)                                                        \
    {                                                                       \
        const float h1 = fmaxf(ux + (WV) * s1l, 0.f);                       \
        float a0 = 0.f, a1 = 0.f, a2 = 0.f, a3 = 0.f;                       \
        _Pragma("unroll")                                                   \
        for (int s = 0; s < I1; s += 4) {                                   \
            a0 = fmaf(rdlane(h1, s + 0), m2col[s + 0], a0);                 \
            a1 = fmaf(rdlane(h1, s + 1), m2col[s + 1], a1);                 \
            a2 = fmaf(rdlane(h1, s + 2), m2col[s + 2], a2);                 \
            a3 = fmaf(rdlane(h1, s + 3), m2col[s + 3], a3);                 \
        }                                                                   \
        const float h2 = fmaxf((a0 + a1) + (a2 + a3) + c2j, 0.f);           \
        float d0a = c30, d0b = 0.f, d1a = c31, d1b = 0.f;                   \
        _Pragma("unroll")                                                   \
        for (int k = 0; k < I2; k += 2) {                                   \
            const float he = rdlane(h2, k);                                 \
            const float ho = rdlane(h2, k + 1);                             \
            d0a = fmaf(he, m3a[k],     d0a);                                \
            d0b = fmaf(ho, m3a[k + 1], d0b);                                \
            d1a = fmaf(he, m3b[k],     d1a);                                \
            d1b = fmaf(ho, m3b[k + 1], d1b);                                \
        }                                                                   \
        acc0 += fmaxf(d0a + d0b, 0.f);                                      \
        acc1 += fmaxf(d1a + d1b, 0.f);                                      \
    }

    // ---- 4. tile loop over active pairs ----
    for (int pt = 0; pt < n; pt += NT) {
        const int te = min(n - pt, NT);

        __syncthreads();                 // vstage reuse guard
        #pragma unroll
        for (int idx = t; idx < NT * PARAM; idx += 256) {
            const int pr = idx >> 7;                 // 0..NT-1
            const int k  = idx & (PARAM - 1);
            const int y  = (pr < te) ? acty[pt + pr] : acty[pt];  // safe dup
            vstage[pr][k] = val[(wbase + y) * PARAM + k];
        }
        __syncthreads();

        // wave w owns tile pairs w and w+4; ONE shared pass over M1bot.
        // vstage reads are uniform-address ds_read_b128 broadcasts.
        const int pA = w, pB = w + 4;
        float WAa = 0.f, WAb = 0.f, WBa = 0.f, WBb = 0.f;   // dual chains
        #pragma unroll 8
        for (int k = 0; k < PARAM; k += 4) {
            const float4 a = *reinterpret_cast<const float4*>(&vstage[pA][k]);
            const float4 b = *reinterpret_cast<const float4*>(&vstage[pB][k]);
            const float m0 = Mlo[(k + 0) * I1 + lane];
            const float m1v = Mlo[(k + 1) * I1 + lane];
            const float m2v = Mlo[(k + 2) * I1 + lane];
            const float m3v = Mlo[(k + 3) * I1 + lane];
            WAa = fmaf(a.x, m0,  WAa);  WAb = fmaf(a.y, m1v, WAb);
            WAa = fmaf(a.z, m2v, WAa);  WAb = fmaf(a.w, m3v, WAb);
            WBa = fmaf(b.x, m0,  WBa);  WBb = fmaf(b.y, m1v, WBb);
            WBa = fmaf(b.z, m2v, WBa);  WBb = fmaf(b.w, m3v, WBb);
        }
        const float WA = WAa + WAb;
        const float WB = WBa + WBb;

        if (pA < te) MLP_BODY(WA)
        if (pB < te) MLP_BODY(WB)
    }
#undef MLP_BODY

    // ---- 5. cross-wave reduce + clip + store ----
    partial[w][lane] = acc0;
    if (lane < 32) partial[w][64 + lane] = acc1;   // halves hold identical acc1
    __syncthreads();

    if (t < PK) {
        float v = (partial[0][t] + partial[1][t] +
                   partial[2][t] + partial[3][t]) * KDIV_INV;
        v = fminf(fmaxf(v, -1.0f), 1.0f);
        out[r * PARAM + KC + t] = v;
    }
}

extern "C" void kernel_launch(void* const* d_in, const int* in_sizes, int n_in,
                              void* d_out, int out_size, void* d_ws, size_t ws_size,
                              hipStream_t stream) {
    const float* mat = (const float*)d_in[0];
    const float* val = (const float*)d_in[1];
    const float* M1  = (const float*)d_in[2];
    const float* B1  = (const float*)d_in[3];
    const float* M2  = (const float*)d_in[4];
    const float* B2  = (const float*)d_in[5];
    const float* M3  = (const float*)d_in[6];
    const float* B3  = (const float*)d_in[7];
    const float* g1  = (const float*)d_in[8];
    const float* b1  = (const float*)d_in[9];
    const float* m1  = (const float*)d_in[10];
    const float* v1  = (const float*)d_in[11];
    const float* g2  = (const float*)d_in[12];
    const float* b2  = (const float*)d_in[13];
    const float* m2  = (const float*)d_in[14];
    const float* v2  = (const float*)d_in[15];
    const float* g3  = (const float*)d_in[16];
    const float* b3  = (const float*)d_in[17];
    const float* m3  = (const float*)d_in[18];
    const float* v3  = (const float*)d_in[19];

    float* out = (float*)d_out;

    hipLaunchKernelGGL(glmlp_one, dim3(NROWS), dim3(256), 0, stream,
                       mat, val, M1, B1, M2, B2, M3, B3,
                       g1, b1, m1, v1, g2, b2, m2, v2, g3, b3, m3, v3,
                       out);
}

// Round 6
// 107.810 us; speedup vs baseline: 1.6574x; 1.3186x over previous
//
#include <hip/hip_runtime.h>

// Problem constants (fixed by reference)
#define GS    256
#define PARAM 128
#define KC    32
#define I1    64
#define I2    32
#define PK    96        // PARAM - KC
#define B_    4
#define NROWS (B_ * GS) // 1024
#define EPS   1e-3f
#define KDIV_INV (1.0f / 16.0f)

// Workspace layout (float offsets)
constexpr int U_OFF   = 0;                   // NROWS*I1
constexpr int W_OFF   = NROWS * I1;
constexpr int M2F_OFF = 2 * NROWS * I1;      // I1*I2
constexpr int C2_OFF  = M2F_OFF + I1 * I2;   // I2
constexpr int M3F_OFF = C2_OFF + I2;         // I2*PK
constexpr int C3_OFF  = M3F_OFF + I2 * PK;   // PK
constexpr int C1_OFF  = C3_OFF + PK;         // I1

__device__ __forceinline__ float rdlane(float v, int l) {
    return __uint_as_float(__builtin_amdgcn_readlane(__float_as_uint(v), l));
}

// Kernel A: one block per row. 256 thr = 64 i-lanes x 4 quarter-dots.
// u = val.(M1top - M1bot) = T - W; compute T and W (1 load per MAC each).
__global__ __launch_bounds__(256) void glmlp_precompute(
    const float* __restrict__ val, const float* __restrict__ M1,
    const float* __restrict__ B1,
    const float* __restrict__ M2, const float* __restrict__ B2,
    const float* __restrict__ M3, const float* __restrict__ B3,
    const float* __restrict__ g1, const float* __restrict__ b1,
    const float* __restrict__ m1, const float* __restrict__ v1,
    const float* __restrict__ g2, const float* __restrict__ b2,
    const float* __restrict__ m2, const float* __restrict__ v2,
    const float* __restrict__ g3, const float* __restrict__ b3,
    const float* __restrict__ m3, const float* __restrict__ v3,
    float* __restrict__ ws, float* __restrict__ out)
{
    const int blk = blockIdx.x;
    const int t = threadIdx.x;

    if (blk < NROWS) {
        __shared__ float vrow[PARAM];
        __shared__ float red[4][I1];
        const int r = blk;
        if (t < PARAM) vrow[t] = val[r * PARAM + t];
        // exact copy: con = val[:, :, :KC] (direct from global; no barrier dep)
        if (t < KC) out[r * PARAM + t] = val[r * PARAM + t];
        __syncthreads();

        const int i = t & (I1 - 1);
        const int q = t >> 6;                         // 0..3
        // q=0,1 -> T (M1 top half); q=2,3 -> W (M1 bottom half)
        const float* __restrict__ Mb = M1 + ((q >> 1) ? (PARAM * I1) : 0);
        const int p0 = (q & 1) * 64;
        float aa = 0.f, bb = 0.f;                     // dual chains (dep 32)
        #pragma unroll 8
        for (int p = 0; p < 64; p += 2) {
            aa = fmaf(vrow[p0 + p],     Mb[(p0 + p) * I1 + i],     aa);
            bb = fmaf(vrow[p0 + p + 1], Mb[(p0 + p + 1) * I1 + i], bb);
        }
        red[q][i] = aa + bb;
        __syncthreads();

        if (q == 0) {
            const float T  = red[0][i] + red[1][i];
            const float Wv = red[2][i] + red[3][i];
            const float s1 = g1[i] * rsqrtf(v1[i] + EPS);
            ws[U_OFF + r * I1 + i] = (T - Wv) * s1;
            ws[W_OFF + r * I1 + i] = Wv * s1;
        }
    } else {
        // BN folding block
        if (t < I1) {
            const float s1 = g1[t] * rsqrtf(v1[t] + EPS);
            ws[C1_OFF + t] = B1[t] * s1 + b1[t] - m1[t] * s1;
        }
        if (t < I2) {
            const float s2 = g2[t] * rsqrtf(v2[t] + EPS);
            ws[C2_OFF + t] = B2[t] * s2 + b2[t] - m2[t] * s2;
        }
        if (t < PK) {
            const float s3 = g3[t] * rsqrtf(v3[t] + EPS);
            ws[C3_OFF + t] = B3[t] * s3 + b3[t] - m3[t] * s3;
        }
        for (int idx = t; idx < I1 * I2; idx += 256) {
            const int j = idx & (I2 - 1);
            const float s2 = g2[j] * rsqrtf(v2[j] + EPS);
            ws[M2F_OFF + idx] = M2[idx] * s2;
        }
        for (int idx = t; idx < I2 * PK; idx += 256) {
            const int k = idx % PK;
            const float s3 = g3[k] * rsqrtf(v3[k] + EPS);
            ws[M3F_OFF + idx] = M3[idx] * s3;
        }
    }
}

// Kernel B: one block per (b,x) row; 4 waves; wave w owns pairs p = w mod 4
// end-to-end. All cross-lane broadcasts via v_readlane (wave-uniform index,
// SGPR result -> scalar operand of v_fma). Weights live in per-lane
// REGISTERS (proven to allocate in this standalone context; the fused/cg
// variants spilled to 80 VGPR three rounds running):
//   lane (h=lane>>5, j=lane&31): m2col[s]=M2f[s][j] (full column, dup across h)
//   m3a[i]=M3f[i][lane] (k=lane), m3b[i]=M3f[i][64+j] (k=64+j, dup across h)
// LDS ~2.6 KB; 2 barriers total.
// r6 change vs r0: W prefetch depth 2 (issue load for pair p+8 before body p)
// — ~2 MLP bodies (~1000 cyc) of L2-latency cover instead of ~1.
__global__ __launch_bounds__(256) void glmlp_pairs(
    const float* __restrict__ mat, const float* __restrict__ ws,
    float* __restrict__ out)
{
    __shared__ int   acty[GS];          // 1 KB
    __shared__ float partial[4][PK];    // 1.5 KB
    __shared__ int   cnt;

    const int r = blockIdx.x;
    const int t = threadIdx.x;
    const int lane = t & 63;
    const int w = t >> 6;               // wave id 0..3
    const int jj = lane & 31;
    const int wbase = r & ~(GS - 1);    // b * GS
    const float* __restrict__ W = ws + W_OFF;

    if (t == 0) cnt = 0;
    const float mv = mat[r * GS + t];

    // register-resident folded weights (coalesced L2-hit loads, once per block)
    float m2col[I1];                    // 64 VGPR
    #pragma unroll
    for (int s = 0; s < I1; ++s)
        m2col[s] = ws[M2F_OFF + s * I2 + jj];
    float m3a[I2], m3b[I2];             // 64 VGPR
    #pragma unroll
    for (int i = 0; i < I2; ++i) {
        m3a[i] = ws[M3F_OFF + i * PK + lane];
        m3b[i] = ws[M3F_OFF + i * PK + 64 + jj];
    }
    const float ux  = ws[U_OFF + r * I1 + lane] + ws[C1_OFF + lane];
    const float c2j = ws[C2_OFF + jj];
    const float c30 = ws[C3_OFF + lane];
    const float c31 = ws[C3_OFF + 64 + jj];

    __syncthreads();                    // cnt=0 visible
    // compact the mask row (values are exactly 0.0/1.0)
    if (mv != 0.0f) acty[atomicAdd(&cnt, 1)] = t;
    __syncthreads();
    const int n = cnt;

    float acc0 = 0.f, acc1 = 0.f;

    // 2-deep software pipeline on the W row loads
    int p = w;
    float wv0 = (p     < n) ? W[(wbase + acty[p    ]) * I1 + lane] : 0.f;
    float wv1 = (p + 4 < n) ? W[(wbase + acty[p + 4]) * I1 + lane] : 0.f;
    while (p < n) {
        const float wv2 = (p + 8 < n) ? W[(wbase + acty[p + 8]) * I1 + lane] : 0.f;

        // Layer 1 (register): lane holds H1[lane]
        const float h1 = fmaxf(ux + wv0, 0.f);

        // Layer 2: every lane computes the FULL dot for its column jj via
        // 64 uniform readlane broadcasts; 4 interleaved chains (dep 16).
        float a0 = 0.f, a1 = 0.f, a2 = 0.f, a3 = 0.f;
        #pragma unroll
        for (int s = 0; s < I1; s += 4) {
            a0 = fmaf(rdlane(h1, s + 0), m2col[s + 0], a0);
            a1 = fmaf(rdlane(h1, s + 1), m2col[s + 1], a1);
            a2 = fmaf(rdlane(h1, s + 2), m2col[s + 2], a2);
            a3 = fmaf(rdlane(h1, s + 3), m2col[s + 3], a3);
        }
        // lane l now holds H2[l & 31] (duplicated across halves)
        const float h2 = fmaxf((a0 + a1) + (a2 + a3) + c2j, 0.f);

        // Layer 3: 32 uniform broadcasts of H2[i] (lane i holds H2[i], i<32);
        // each serves both output columns k0=lane, k1=64+jj. Dual chains each.
        float d0a = c30, d0b = 0.f, d1a = c31, d1b = 0.f;
        #pragma unroll
        for (int i = 0; i < I2; i += 2) {
            const float he = rdlane(h2, i);
            const float ho = rdlane(h2, i + 1);
            d0a = fmaf(he, m3a[i],     d0a);
            d0b = fmaf(ho, m3a[i + 1], d0b);
            d1a = fmaf(he, m3b[i],     d1a);
            d1b = fmaf(ho, m3b[i + 1], d1b);
        }
        acc0 += fmaxf(d0a + d0b, 0.f);
        acc1 += fmaxf(d1a + d1b, 0.f);

        wv0 = wv1;
        wv1 = wv2;
        p += 4;
    }

    partial[w][lane] = acc0;
    if (lane < 32) partial[w][64 + lane] = acc1;   // halves hold identical acc1
    __syncthreads();

    if (t < PK) {
        float v = (partial[0][t] + partial[1][t] + partial[2][t] + partial[3][t])
                  * KDIV_INV;
        v = fminf(fmaxf(v, -1.0f), 1.0f);
        out[r * PARAM + KC + t] = v;
    }
}

extern "C" void kernel_launch(void* const* d_in, const int* in_sizes, int n_in,
                              void* d_out, int out_size, void* d_ws, size_t ws_size,
                              hipStream_t stream) {
    const float* mat = (const float*)d_in[0];
    const float* val = (const float*)d_in[1];
    const float* M1  = (const float*)d_in[2];
    const float* B1  = (const float*)d_in[3];
    const float* M2  = (const float*)d_in[4];
    const float* B2  = (const float*)d_in[5];
    const float* M3  = (const float*)d_in[6];
    const float* B3  = (const float*)d_in[7];
    const float* g1  = (const float*)d_in[8];
    const float* b1  = (const float*)d_in[9];
    const float* m1  = (const float*)d_in[10];
    const float* v1  = (const float*)d_in[11];
    const float* g2  = (const float*)d_in[12];
    const float* b2  = (const float*)d_in[13];
    const float* m2  = (const float*)d_in[14];
    const float* v2  = (const float*)d_in[15];
    const float* g3  = (const float*)d_in[16];
    const float* b3  = (const float*)d_in[17];
    const float* m3  = (const float*)d_in[18];
    const float* v3  = (const float*)d_in[19];

    float* ws  = (float*)d_ws;
    float* out = (float*)d_out;

    hipLaunchKernelGGL(glmlp_precompute, dim3(NROWS + 1), dim3(256), 0, stream,
                       val, M1, B1, M2, B2, M3, B3,
                       g1, b1, m1, v1, g2, b2, m2, v2, g3, b3, m3, v3,
                       ws, out);

    hipLaunchKernelGGL(glmlp_pairs, dim3(NROWS), dim3(256), 0, stream,
                       mat, ws, out);
}